// Round 1
// baseline (311.994 us; speedup 1.0000x reference)
//
#include <hip/hip_runtime.h>
#include <stdint.h>

#define T_LEN 524288
#define NCHUNK 1024
#define WARMUP 192

// ---- workspace layout (bytes) ----
static const size_t OFF_MASK = 0;                       // T uint8
static const size_t OFF_SEG  = 524288;                  // T int   (segment index per t)
static const size_t OFF_SPK  = OFF_SEG + 4ull*T_LEN;    // T int   (spike times)
static const size_t OFF_INP2 = OFF_SPK + 4ull*T_LEN;    // T float2 (x_t, delta)
static const size_t OFF_A    = OFF_INP2 + 8ull*T_LEN;   // T float
static const size_t OFF_B    = OFF_A + 4ull*T_LEN;      // T float
static const size_t OFF_CNT  = OFF_B + 4ull*T_LEN;      // 512 int
static const size_t OFF_BOFF = OFF_CNT + 4ull*512;      // 512 int
static const size_t OFF_N    = OFF_BOFF + 4ull*512;     // 1 int
static const size_t OFF_H    = 16777216;                // N*32 float (h after each spike)

// ---- K1: spike mask (exact fp64 window RMS) ----
__global__ __launch_bounds__(256) void k_mask(const float* __restrict__ x,
                                              uint8_t* __restrict__ mask,
                                              float* __restrict__ out, int out_size)
{
    __shared__ float tile[386];
    const int bs = blockIdx.x * 256;
    const int tid = threadIdx.x;
    for (int j = tid; j < 386; j += 256) {
        int g = bs - 130 + j;
        tile[j] = (g >= 0) ? x[g] : 0.f;
    }
    __syncthreads();
    const int t = bs + tid;
    double s = 0.0;
    #pragma unroll 8
    for (int m = 0; m < 128; ++m) {   // window [t-128, t), zero-padded below 0
        double v = (double)tile[tid + 2 + m];
        s = fma(v, v, s);
    }
    int cnt = t < 128 ? (t < 1 ? 1 : t) : 128;
    double rms = sqrt(s / (double)cnt) + 1e-8;
    double xt  = (double)tile[tid + 130];
    double pr  = 2.0 * (double)tile[tid + 129] - (double)tile[tid + 128];
    double err = fabs(xt - pr);
    bool m = (t < 2) || (err > 2.5 * rms);
    mask[t] = m ? 1 : 0;
    int oi = T_LEN + 1 + t;
    if (oi < out_size) out[oi] = m ? 1.f : 0.f;
}

// ---- K2: per-block spike counts (1024 elems/block) ----
__global__ __launch_bounds__(256) void k_count(const uint8_t* __restrict__ mask,
                                               int* __restrict__ cnt)
{
    __shared__ int tot;
    if (threadIdx.x == 0) tot = 0;
    __syncthreads();
    int base = blockIdx.x * 1024 + threadIdx.x * 4;
    uchar4 v = *(const uchar4*)(mask + base);
    int s = (int)v.x + v.y + v.z + v.w;
    for (int d = 32; d; d >>= 1) s += __shfl_down(s, d, 64);
    if ((threadIdx.x & 63) == 0) atomicAdd(&tot, s);
    __syncthreads();
    if (threadIdx.x == 0) cnt[blockIdx.x] = tot;
}

// ---- K3: scan of 512 block counts ----
__global__ __launch_bounds__(512) void k_scan(const int* __restrict__ cnt,
                                              int* __restrict__ boff,
                                              int* __restrict__ nspk,
                                              float* __restrict__ out, int out_size)
{
    __shared__ int buf[2][512];
    int t = threadIdx.x;
    int v = cnt[t];
    buf[0][t] = v;
    __syncthreads();
    int src = 0;
    for (int d = 1; d < 512; d <<= 1) {
        int nv = buf[src][t] + (t >= d ? buf[src][t - d] : 0);
        buf[src ^ 1][t] = nv;
        __syncthreads();
        src ^= 1;
    }
    boff[t] = buf[src][t] - v;
    if (t == 511) {
        int tot = buf[src][511];
        *nspk = tot;
        if (T_LEN < out_size) out[T_LEN] = (float)tot;
    }
}

// ---- K4: scatter spike times + per-t segment index ----
__global__ __launch_bounds__(256) void k_scatter(const uint8_t* __restrict__ mask,
                                                 const int* __restrict__ boff,
                                                 int* __restrict__ seg,
                                                 int* __restrict__ spk)
{
    __shared__ int wtot[4];
    const int tid = threadIdx.x, b = blockIdx.x;
    const int base = b * 1024 + tid * 4;
    uchar4 mv = *(const uchar4*)(mask + base);
    int m0 = mv.x, m1 = mv.y, m2 = mv.z, m3 = mv.w;
    int e1 = m0, e2 = m0 + m1, e3 = m0 + m1 + m2, tsum = e3 + m3;
    int lane = tid & 63, w = tid >> 6;
    int incl = tsum;
    for (int d = 1; d < 64; d <<= 1) {
        int u = __shfl_up(incl, d, 64);
        if (lane >= d) incl += u;
    }
    if (lane == 63) wtot[w] = incl;
    __syncthreads();
    int woff = 0;
    for (int i = 0; i < w; i++) woff += wtot[i];
    int texcl = woff + incl - tsum;
    int g0 = boff[b] + texcl;
    int e[4] = {0, e1, e2, e3};
    int m[4] = {m0, m1, m2, m3};
    #pragma unroll
    for (int k = 0; k < 4; k++) {
        int excl = g0 + e[k];
        seg[base + k] = excl + m[k] - 1;  // inclusive count - 1 = last spike idx <= t
        if (m[k]) spk[excl] = base + k;
    }
}

// ---- K4b: per-spike GRU inputs (x_t, delta) ----
__global__ __launch_bounds__(256) void k_inp(const int* __restrict__ spk,
                                             const float* __restrict__ x,
                                             const int* __restrict__ nspk,
                                             float2* __restrict__ inp2)
{
    int s = blockIdx.x * 256 + threadIdx.x;
    if (s >= *nspk) return;
    int t = spk[s];
    int tp = s ? spk[s - 1] : 0;
    inp2[s] = make_float2(x[t], (float)(t - tp) * 0.0078125f);
}

// ---- K5: the sequential GRU chain, chunked with warmup ----
__global__ __launch_bounds__(64, 1) void k_chain(const float* __restrict__ Whh,
                                                 const float* __restrict__ Wih,
                                                 const float* __restrict__ bih,
                                                 const float* __restrict__ bhh,
                                                 const float2* __restrict__ inp2,
                                                 const int* __restrict__ nspk,
                                                 float* __restrict__ Hbuf)
{
    const int lane = threadIdx.x;
    const int N = *nspk;
    const int c = blockIdx.x;
    const int L = (N + NCHUNK - 1) / NCHUNK;
    const int start = c * L;
    if (start >= N) return;
    const int end = min(start + L, N);
    const int s0 = max(start - WARMUP, 0);
    const int i = lane & 31;

    float Wr[32], Wz[32], Wn[32];
    #pragma unroll
    for (int k = 0; k < 32; k++) {
        Wr[k] = Whh[i * 32 + k];
        Wz[k] = Whh[(32 + i) * 32 + k];
        Wn[k] = Whh[(64 + i) * 32 + k];
    }
    const float wr0 = Wih[i * 2],        wr1 = Wih[i * 2 + 1];
    const float wz0 = Wih[(32 + i) * 2], wz1 = Wih[(32 + i) * 2 + 1];
    const float wn0 = Wih[(64 + i) * 2], wn1 = Wih[(64 + i) * 2 + 1];
    const float br  = bih[i] + bhh[i];
    const float bz  = bih[32 + i] + bhh[32 + i];
    const float bnh = bhh[64 + i];
    const float bni = bih[64 + i];

    float hs[32];
    #pragma unroll
    for (int k = 0; k < 32; k++) hs[k] = 0.f;
    float hi = 0.f;

    float2 cur = inp2[s0];
    for (int s = s0; s < end; ++s) {
        float2 nxt = inp2[min(s + 1, end - 1)];   // 1-deep prefetch
        float ar  = fmaf(wr1, cur.y, fmaf(wr0, cur.x, br));
        float az  = fmaf(wz1, cur.y, fmaf(wz0, cur.x, bz));
        float gin = fmaf(wn1, cur.y, fmaf(wn0, cur.x, bni));
        float an  = bnh;
        #pragma unroll
        for (int k = 0; k < 32; k++) {            // 96 FMAs, SGPR h operand
            float h = hs[k];
            ar = fmaf(Wr[k], h, ar);
            az = fmaf(Wz[k], h, az);
            an = fmaf(Wn[k], h, an);
        }
        float r = __builtin_amdgcn_rcpf(1.f + __builtin_amdgcn_exp2f(-1.44269504089f * ar));
        float z = __builtin_amdgcn_rcpf(1.f + __builtin_amdgcn_exp2f(-1.44269504089f * az));
        float npre = fmaf(r, an, gin);
        float en = __builtin_amdgcn_exp2f(2.88539008178f * npre);
        float n = fmaf(-2.f, __builtin_amdgcn_rcpf(1.f + en), 1.f);
        hi = fmaf(z, hi - n, n);
        if (s >= start && lane < 32) Hbuf[(size_t)s * 32 + i] = hi;  // fire-and-forget
        int hb = __float_as_int(hi);
        #pragma unroll
        for (int k = 0; k < 32; k++)              // broadcast h -> SGPRs
            hs[k] = __int_as_float(__builtin_amdgcn_readlane(hb, k));
        cur = nxt;
    }
}

// ---- K6a: per-spike output scalars a = h@Wv+bv, b = h@Ws+bs ----
__global__ __launch_bounds__(256) void k_ab(const float* __restrict__ Hbuf,
                                            const float* __restrict__ Wv,
                                            const float* __restrict__ Wsc,
                                            const float* __restrict__ bv,
                                            const float* __restrict__ bs,
                                            const int* __restrict__ nspk,
                                            float* __restrict__ A, float* __restrict__ B)
{
    int s = blockIdx.x * 256 + threadIdx.x;
    if (s >= *nspk) return;
    float a = *bv, b = *bs;
    const float* h = Hbuf + (size_t)s * 32;
    #pragma unroll
    for (int k = 0; k < 32; k++) {
        float hv = h[k];
        a = fmaf(hv, Wv[k], a);
        b = fmaf(hv, Wsc[k], b);
    }
    A[s] = a; B[s] = b;
}

// ---- K6b: expand outputs over all t ----
__global__ __launch_bounds__(256) void k_out(const int* __restrict__ seg,
                                             const int* __restrict__ spk,
                                             const float* __restrict__ A,
                                             const float* __restrict__ B,
                                             float* __restrict__ out)
{
    int t = blockIdx.x * 256 + threadIdx.x;
    int p = seg[t];
    int tp = spk[p];
    out[t] = fmaf(B[p], (float)(t - tp) * 0.0078125f, A[p]);
}

extern "C" void kernel_launch(void* const* d_in, const int* in_sizes, int n_in,
                              void* d_out, int out_size, void* d_ws, size_t ws_size,
                              hipStream_t stream)
{
    const float* x   = (const float*)d_in[0];
    const float* Wih = (const float*)d_in[1];
    const float* Whh = (const float*)d_in[2];
    const float* bih = (const float*)d_in[3];
    const float* bhh = (const float*)d_in[4];
    const float* Wv  = (const float*)d_in[5];
    const float* bv  = (const float*)d_in[6];
    const float* Wsc = (const float*)d_in[7];
    const float* bs  = (const float*)d_in[8];
    float* out = (float*)d_out;

    char* ws = (char*)d_ws;
    uint8_t* mask = (uint8_t*)(ws + OFF_MASK);
    int*    seg   = (int*)(ws + OFF_SEG);
    int*    spk   = (int*)(ws + OFF_SPK);
    float2* inp2  = (float2*)(ws + OFF_INP2);
    float*  A     = (float*)(ws + OFF_A);
    float*  B     = (float*)(ws + OFF_B);
    int*    cnt   = (int*)(ws + OFF_CNT);
    int*    boff  = (int*)(ws + OFF_BOFF);
    int*    nspk  = (int*)(ws + OFF_N);
    float*  Hbuf  = (float*)(ws + OFF_H);

    k_mask<<<2048, 256, 0, stream>>>(x, mask, out, out_size);
    k_count<<<512, 256, 0, stream>>>(mask, cnt);
    k_scan<<<1, 512, 0, stream>>>(cnt, boff, nspk, out, out_size);
    k_scatter<<<512, 256, 0, stream>>>(mask, boff, seg, spk);
    k_inp<<<2048, 256, 0, stream>>>(spk, x, nspk, inp2);
    k_chain<<<NCHUNK, 64, 0, stream>>>(Whh, Wih, bih, bhh, inp2, nspk, Hbuf);
    k_ab<<<2048, 256, 0, stream>>>(Hbuf, Wv, Wsc, bv, bs, nspk, A, B);
    k_out<<<2048, 256, 0, stream>>>(seg, spk, A, B, out);
}

// Round 2
// 229.427 us; speedup vs baseline: 1.3599x; 1.3599x over previous
//
#include <hip/hip_runtime.h>
#include <stdint.h>

#define T_LEN 524288
#define NCHUNK 1024
#define WARMUP 64

// ---- workspace layout (bytes) ----
static const size_t OFF_MASK = 0;                       // T uint8
static const size_t OFF_SEG  = 524288;                  // T int   (segment index per t)
static const size_t OFF_SPK  = OFF_SEG + 4ull*T_LEN;    // T int   (spike times)
static const size_t OFF_A    = OFF_SPK + 4ull*T_LEN;    // T float
static const size_t OFF_B    = OFF_A + 4ull*T_LEN;      // T float
static const size_t OFF_CNT  = OFF_B + 4ull*T_LEN;      // 512 int
static const size_t OFF_BOFF = OFF_CNT + 4ull*512;      // 512 int
static const size_t OFF_N    = OFF_BOFF + 4ull*512;     // 1 int
static const size_t OFF_H    = 16777216;                // N*32 float (h after each spike)

// ---- K1: spike mask (fp32 rolling window RMS) + per-1024-block spike count ----
__global__ __launch_bounds__(256) void k_mask(const float* __restrict__ x,
                                              uint8_t* __restrict__ mask,
                                              float* __restrict__ out, int out_size,
                                              int* __restrict__ cnt)
{
    __shared__ float tile[1154];          // x[bs-130 .. bs+1024)
    __shared__ int tot;
    const int bs = blockIdx.x * 1024;
    const int tid = threadIdx.x;
    if (tid == 0) tot = 0;
    for (int j = tid; j < 1154; j += 256) {
        int g = bs - 130 + j;
        tile[j] = (g >= 0) ? x[g] : 0.f;
    }
    __syncthreads();

    const int loc = tid * 4;              // local index of first element
    // initial window sum for t0 = bs + loc: terms tile[loc+2 .. loc+130)
    float s = 0.f;
    #pragma unroll 16
    for (int m = 0; m < 128; ++m) {
        float v = tile[loc + 2 + m];
        s = fmaf(v, v, s);
    }
    uchar4 mv;
    float4 mf;
    int msum = 0;
    uint8_t* mp = &mv.x;
    float*   fp = &mf.x;
    #pragma unroll
    for (int it = 0; it < 4; ++it) {
        int t = bs + loc + it;
        int c = t < 128 ? (t < 1 ? 1 : t) : 128;
        float rms = sqrtf(fmaxf(s, 0.f) / (float)c) + 1e-8f;
        float xt = tile[loc + 130 + it];
        float pr = 2.f * tile[loc + 129 + it] - tile[loc + 128 + it];
        float err = fabsf(xt - pr);
        bool m = (t < 2) || (err > 2.5f * rms);
        mp[it] = m ? 1 : 0;
        fp[it] = m ? 1.f : 0.f;
        msum += m ? 1 : 0;
        // roll window: add x[t]^2, drop x[t-128]^2
        float a = tile[loc + 130 + it], d = tile[loc + 2 + it];
        s = fmaf(a, a, s) - d * d;
    }
    *(uchar4*)(mask + bs + loc) = mv;
    int oi = T_LEN + 1 + bs + loc;
    if (oi + 3 < out_size) *(float4*)(out + oi) = mf;

    for (int d = 32; d; d >>= 1) msum += __shfl_down(msum, d, 64);
    if ((tid & 63) == 0) atomicAdd(&tot, msum);
    __syncthreads();
    if (tid == 0) cnt[blockIdx.x] = tot;
}

// ---- K2: scan of 512 block counts ----
__global__ __launch_bounds__(512) void k_scan(const int* __restrict__ cnt,
                                              int* __restrict__ boff,
                                              int* __restrict__ nspk,
                                              float* __restrict__ out, int out_size)
{
    __shared__ int buf[2][512];
    int t = threadIdx.x;
    int v = cnt[t];
    buf[0][t] = v;
    __syncthreads();
    int src = 0;
    for (int d = 1; d < 512; d <<= 1) {
        int nv = buf[src][t] + (t >= d ? buf[src][t - d] : 0);
        buf[src ^ 1][t] = nv;
        __syncthreads();
        src ^= 1;
    }
    boff[t] = buf[src][t] - v;
    if (t == 511) {
        int tot = buf[src][511];
        *nspk = tot;
        if (T_LEN < out_size) out[T_LEN] = (float)tot;
    }
}

// ---- K3: scatter spike times + per-t segment index ----
__global__ __launch_bounds__(256) void k_scatter(const uint8_t* __restrict__ mask,
                                                 const int* __restrict__ boff,
                                                 int* __restrict__ seg,
                                                 int* __restrict__ spk)
{
    __shared__ int wtot[4];
    const int tid = threadIdx.x, b = blockIdx.x;
    const int base = b * 1024 + tid * 4;
    uchar4 mv = *(const uchar4*)(mask + base);
    int m0 = mv.x, m1 = mv.y, m2 = mv.z, m3 = mv.w;
    int e1 = m0, e2 = m0 + m1, e3 = m0 + m1 + m2, tsum = e3 + m3;
    int lane = tid & 63, w = tid >> 6;
    int incl = tsum;
    for (int d = 1; d < 64; d <<= 1) {
        int u = __shfl_up(incl, d, 64);
        if (lane >= d) incl += u;
    }
    if (lane == 63) wtot[w] = incl;
    __syncthreads();
    int woff = 0;
    for (int i = 0; i < w; i++) woff += wtot[i];
    int texcl = woff + incl - tsum;
    int g0 = boff[b] + texcl;
    int e[4] = {0, e1, e2, e3};
    int m[4] = {m0, m1, m2, m3};
    #pragma unroll
    for (int k = 0; k < 4; k++) {
        int excl = g0 + e[k];
        seg[base + k] = excl + m[k] - 1;  // last spike idx <= t
        if (m[k]) spk[excl] = base + k;
    }
}

// ---- K4: sequential GRU chain, chunked with warmup ----
// Lane layout: i = lane&31, half = lane>>5.
//  lanes 0-31  own r-row i ; lanes 32-63 own z-row i ; n-row i duplicated on both.
//  h_i lives on lane 32+i (per-lane reg) and is broadcast to SGPRs for the matvec.
__global__ __launch_bounds__(64, 1) void k_chain(const float* __restrict__ Whh,
                                                 const float* __restrict__ Wih,
                                                 const float* __restrict__ bih,
                                                 const float* __restrict__ bhh,
                                                 const int* __restrict__ spk,
                                                 const float* __restrict__ x,
                                                 const int* __restrict__ nspk,
                                                 float* __restrict__ Hbuf)
{
    const int lane = threadIdx.x;
    const int N = *nspk;
    const int c = blockIdx.x;
    const int L = (N + NCHUNK - 1) / NCHUNK;
    const int start = c * L;
    if (start >= N) return;
    const int end = min(start + L, N);
    const int s0 = max(start - WARMUP, 0);
    const int cnt = end - s0;             // <= L + WARMUP
    const int jw = start - s0;            // first j whose h is stored
    const int i = lane & 31;
    const int half = lane >> 5;
    const int rown = half ? 32 + i : i;

    // per-lane weights: own (r or z) row + duplicated n row
    float Wo[32], Wn[32];
    #pragma unroll
    for (int k = 0; k < 32; k++) {
        Wo[k] = Whh[rown * 32 + k];
        Wn[k] = Whh[(64 + i) * 32 + k];
    }
    const float wo0 = Wih[rown * 2],     wo1 = Wih[rown * 2 + 1];
    const float wn0 = Wih[(64 + i) * 2], wn1 = Wih[(64 + i) * 2 + 1];
    const float bo  = bih[rown] + bhh[rown];
    const float bni = bih[64 + i];
    const float bnh = bhh[64 + i];

    // stage (t, x_t) pairs for steps [s0-1 .. end) into LDS
    __shared__ float2 sx[608];            // worst case L<=512: cnt+1 <= 577
    for (int j = lane; j < cnt + 1; j += 64) {
        int idx = s0 - 1 + j;
        idx = idx < 0 ? 0 : idx;
        int t = spk[idx];
        sx[j] = make_float2((float)t, x[t]);
    }
    __syncthreads();

    float hs[32];
    #pragma unroll
    for (int k = 0; k < 32; k++) hs[k] = 0.f;
    float hold = 0.f;                     // h_i on lane 32+i

    float2 p0 = sx[0], p1 = sx[1];
    for (int j = 0; j < cnt; ++j) {
        float2 p2 = sx[j + 2 < cnt ? j + 2 : cnt];   // 1-deep LDS prefetch
        float d  = (p1.x - p0.x) * 0.0078125f;
        float xt = p1.y;

        float ao0 = fmaf(wo1, d, fmaf(wo0, xt, bo));
        float gin = fmaf(wn1, d, fmaf(wn0, xt, bni));
        float ao1 = 0.f, an0 = bnh, an1 = 0.f;
        #pragma unroll
        for (int k = 0; k < 16; k++) {    // 4 chains of depth 16, 64 FMAs total
            ao0 = fmaf(Wo[k],      hs[k],      ao0);
            ao1 = fmaf(Wo[k + 16], hs[k + 16], ao1);
            an0 = fmaf(Wn[k],      hs[k],      an0);
            an1 = fmaf(Wn[k + 16], hs[k + 16], an1);
        }
        float ao = ao0 + ao1;
        float an = an0 + an1;
        // sigmoid wave-wide: lanes<32 -> r_i, lanes>=32 -> z_i
        float g = __builtin_amdgcn_rcpf(1.f + __builtin_amdgcn_exp2f(-1.44269504089f * ao));
        float r = __shfl(g, i, 64);       // both halves read lane i's r
        float npre = fmaf(r, an, gin);
        float en = __builtin_amdgcn_exp2f(2.88539008178f * npre);
        float n = fmaf(-2.f, __builtin_amdgcn_rcpf(1.f + en), 1.f);
        float hnew = fmaf(g, hold - n, n);   // valid on upper half (g = z)
        hold = hnew;
        if (j >= jw && lane >= 32)
            Hbuf[(size_t)(s0 + j) * 32 + i] = hnew;   // fire-and-forget
        int hb = __float_as_int(hnew);
        #pragma unroll
        for (int k = 0; k < 32; k++)
            hs[k] = __int_as_float(__builtin_amdgcn_readlane(hb, 32 + k));
        p0 = p1; p1 = p2;
    }
}

// ---- K5: per-spike output scalars a = h@Wv+bv, b = h@Ws+bs ----
__global__ __launch_bounds__(256) void k_ab(const float* __restrict__ Hbuf,
                                            const float* __restrict__ Wv,
                                            const float* __restrict__ Wsc,
                                            const float* __restrict__ bv,
                                            const float* __restrict__ bs,
                                            const int* __restrict__ nspk,
                                            float* __restrict__ A, float* __restrict__ B)
{
    int s = blockIdx.x * 256 + threadIdx.x;
    if (s >= *nspk) return;
    float a = *bv, b = *bs;
    const float4* h4 = (const float4*)(Hbuf + (size_t)s * 32);
    #pragma unroll
    for (int q = 0; q < 8; q++) {
        float4 hv = h4[q];
        a = fmaf(hv.x, Wv[q*4+0], a); b = fmaf(hv.x, Wsc[q*4+0], b);
        a = fmaf(hv.y, Wv[q*4+1], a); b = fmaf(hv.y, Wsc[q*4+1], b);
        a = fmaf(hv.z, Wv[q*4+2], a); b = fmaf(hv.z, Wsc[q*4+2], b);
        a = fmaf(hv.w, Wv[q*4+3], a); b = fmaf(hv.w, Wsc[q*4+3], b);
    }
    A[s] = a; B[s] = b;
}

// ---- K6: expand outputs over all t ----
__global__ __launch_bounds__(256) void k_out(const int* __restrict__ seg,
                                             const int* __restrict__ spk,
                                             const float* __restrict__ A,
                                             const float* __restrict__ B,
                                             float* __restrict__ out)
{
    int t = blockIdx.x * 256 + threadIdx.x;
    int p = seg[t];
    int tp = spk[p];
    out[t] = fmaf(B[p], (float)(t - tp) * 0.0078125f, A[p]);
}

extern "C" void kernel_launch(void* const* d_in, const int* in_sizes, int n_in,
                              void* d_out, int out_size, void* d_ws, size_t ws_size,
                              hipStream_t stream)
{
    const float* x   = (const float*)d_in[0];
    const float* Wih = (const float*)d_in[1];
    const float* Whh = (const float*)d_in[2];
    const float* bih = (const float*)d_in[3];
    const float* bhh = (const float*)d_in[4];
    const float* Wv  = (const float*)d_in[5];
    const float* bv  = (const float*)d_in[6];
    const float* Wsc = (const float*)d_in[7];
    const float* bs  = (const float*)d_in[8];
    float* out = (float*)d_out;

    char* ws = (char*)d_ws;
    uint8_t* mask = (uint8_t*)(ws + OFF_MASK);
    int*    seg   = (int*)(ws + OFF_SEG);
    int*    spk   = (int*)(ws + OFF_SPK);
    float*  A     = (float*)(ws + OFF_A);
    float*  B     = (float*)(ws + OFF_B);
    int*    cnt   = (int*)(ws + OFF_CNT);
    int*    boff  = (int*)(ws + OFF_BOFF);
    int*    nspk  = (int*)(ws + OFF_N);
    float*  Hbuf  = (float*)(ws + OFF_H);

    k_mask<<<512, 256, 0, stream>>>(x, mask, out, out_size, cnt);
    k_scan<<<1, 512, 0, stream>>>(cnt, boff, nspk, out, out_size);
    k_scatter<<<512, 256, 0, stream>>>(mask, boff, seg, spk);
    k_chain<<<NCHUNK, 64, 0, stream>>>(Whh, Wih, bih, bhh, spk, x, nspk, Hbuf);
    k_ab<<<2048, 256, 0, stream>>>(Hbuf, Wv, Wsc, bv, bs, nspk, A, B);
    k_out<<<2048, 256, 0, stream>>>(seg, spk, A, B, out);
}

// Round 3
// 184.551 us; speedup vs baseline: 1.6906x; 1.2432x over previous
//
#include <hip/hip_runtime.h>
#include <stdint.h>

#define T_LEN 524288
#define NCHUNK 1024
#define WARMUP 64
#define LMAX 224          // max steps stored per chunk (N=161792 -> L=158)

// ---- workspace layout (bytes) ----
static const size_t OFF_MASK = 0;                       // T uint8
static const size_t OFF_SEG  = 524288;                  // T int
static const size_t OFF_SPK  = OFF_SEG + 4ull*T_LEN;    // T int
static const size_t OFF_A    = OFF_SPK + 4ull*T_LEN;    // T float
static const size_t OFF_B    = OFF_A + 4ull*T_LEN;      // T float
static const size_t OFF_CNT  = OFF_B + 4ull*T_LEN;      // 512 int
static const size_t OFF_BOFF = OFF_CNT + 4ull*512;      // 512 int
static const size_t OFF_N    = OFF_BOFF + 4ull*512;     // 1 int

// ---- K1: spike mask (fp32 rolling window RMS) + per-1024-block spike count ----
__global__ __launch_bounds__(256) void k_mask(const float* __restrict__ x,
                                              uint8_t* __restrict__ mask,
                                              float* __restrict__ out, int out_size,
                                              int* __restrict__ cnt)
{
    __shared__ float tile[1154];          // x[bs-130 .. bs+1024)
    __shared__ int tot;
    const int bs = blockIdx.x * 1024;
    const int tid = threadIdx.x;
    if (tid == 0) tot = 0;
    for (int j = tid; j < 1154; j += 256) {
        int g = bs - 130 + j;
        tile[j] = (g >= 0) ? x[g] : 0.f;
    }
    __syncthreads();

    const int loc = tid * 4;
    float s = 0.f;
    #pragma unroll 16
    for (int m = 0; m < 128; ++m) {
        float v = tile[loc + 2 + m];
        s = fmaf(v, v, s);
    }
    uchar4 mv;
    float4 mf;
    int msum = 0;
    uint8_t* mp = &mv.x;
    float*   fp = &mf.x;
    #pragma unroll
    for (int it = 0; it < 4; ++it) {
        int t = bs + loc + it;
        int c = t < 128 ? (t < 1 ? 1 : t) : 128;
        float rms = sqrtf(fmaxf(s, 0.f) / (float)c) + 1e-8f;
        float xt = tile[loc + 130 + it];
        float pr = 2.f * tile[loc + 129 + it] - tile[loc + 128 + it];
        float err = fabsf(xt - pr);
        bool m = (t < 2) || (err > 2.5f * rms);
        mp[it] = m ? 1 : 0;
        fp[it] = m ? 1.f : 0.f;
        msum += m ? 1 : 0;
        float a = tile[loc + 130 + it], d = tile[loc + 2 + it];
        s = fmaf(a, a, s) - d * d;
    }
    *(uchar4*)(mask + bs + loc) = mv;
    int oi = T_LEN + 1 + bs + loc;
    if (oi + 3 < out_size) *(float4*)(out + oi) = mf;

    for (int d = 32; d; d >>= 1) msum += __shfl_down(msum, d, 64);
    if ((tid & 63) == 0) atomicAdd(&tot, msum);
    __syncthreads();
    if (tid == 0) cnt[blockIdx.x] = tot;
}

// ---- K2: scan of 512 block counts ----
__global__ __launch_bounds__(512) void k_scan(const int* __restrict__ cnt,
                                              int* __restrict__ boff,
                                              int* __restrict__ nspk,
                                              float* __restrict__ out, int out_size)
{
    __shared__ int buf[2][512];
    int t = threadIdx.x;
    int v = cnt[t];
    buf[0][t] = v;
    __syncthreads();
    int src = 0;
    for (int d = 1; d < 512; d <<= 1) {
        int nv = buf[src][t] + (t >= d ? buf[src][t - d] : 0);
        buf[src ^ 1][t] = nv;
        __syncthreads();
        src ^= 1;
    }
    boff[t] = buf[src][t] - v;
    if (t == 511) {
        int tot = buf[src][511];
        *nspk = tot;
        if (T_LEN < out_size) out[T_LEN] = (float)tot;
    }
}

// ---- K3: scatter spike times + per-t segment index ----
__global__ __launch_bounds__(256) void k_scatter(const uint8_t* __restrict__ mask,
                                                 const int* __restrict__ boff,
                                                 int* __restrict__ seg,
                                                 int* __restrict__ spk)
{
    __shared__ int wtot[4];
    const int tid = threadIdx.x, b = blockIdx.x;
    const int base = b * 1024 + tid * 4;
    uchar4 mv = *(const uchar4*)(mask + base);
    int m0 = mv.x, m1 = mv.y, m2 = mv.z, m3 = mv.w;
    int e1 = m0, e2 = m0 + m1, e3 = m0 + m1 + m2, tsum = e3 + m3;
    int lane = tid & 63, w = tid >> 6;
    int incl = tsum;
    for (int d = 1; d < 64; d <<= 1) {
        int u = __shfl_up(incl, d, 64);
        if (lane >= d) incl += u;
    }
    if (lane == 63) wtot[w] = incl;
    __syncthreads();
    int woff = 0;
    for (int i = 0; i < w; i++) woff += wtot[i];
    int texcl = woff + incl - tsum;
    int g0 = boff[b] + texcl;
    int e[4] = {0, e1, e2, e3};
    int m[4] = {m0, m1, m2, m3};
    #pragma unroll
    for (int k = 0; k < 4; k++) {
        int excl = g0 + e[k];
        seg[base + k] = excl + m[k] - 1;
        if (m[k]) spk[excl] = base + k;
    }
}

// ---- K4: sequential GRU chain; h history in LDS; A/B computed in epilogue ----
// All 64 lanes redundantly compute row i = lane&31 (no cross-half shuffle).
// h broadcast via v_readlane into scalar regs. Weights stay in VGPRs thanks
// to amdgpu_waves_per_eu(1,1) (512-VGPR budget; the default heuristic spilled).
__global__ __attribute__((amdgpu_waves_per_eu(1, 1)))
__launch_bounds__(64) void k_chain(const float* __restrict__ Whh,
                                   const float* __restrict__ Wih,
                                   const float* __restrict__ bih,
                                   const float* __restrict__ bhh,
                                   const int* __restrict__ spk,
                                   const float* __restrict__ x,
                                   const int* __restrict__ nspk,
                                   const float* __restrict__ Wv,
                                   const float* __restrict__ Wsc,
                                   const float* __restrict__ bv,
                                   const float* __restrict__ bs,
                                   float* __restrict__ A,
                                   float* __restrict__ B)
{
    const int lane = threadIdx.x;
    const int N = *nspk;
    const int c = blockIdx.x;
    const int L = (N + NCHUNK - 1) / NCHUNK;   // 158 for N=161792 (<= LMAX)
    const int start = c * L;
    if (start >= N) return;
    const int end = min(start + L, N);
    const int s0 = max(start - WARMUP, 0);
    const int cnt = end - s0;
    const int jw = start - s0;
    const int i = lane & 31;

    // per-lane weights (VGPRs)
    float Wr[32], Wz[32], Wn[32];
    #pragma unroll
    for (int k = 0; k < 32; k++) {
        Wr[k] = Whh[i * 32 + k];
        Wz[k] = Whh[(32 + i) * 32 + k];
        Wn[k] = Whh[(64 + i) * 32 + k];
    }
    const float wr0 = Wih[i * 2],        wr1 = Wih[i * 2 + 1];
    const float wz0 = Wih[(32 + i) * 2], wz1 = Wih[(32 + i) * 2 + 1];
    const float wn0 = Wih[(64 + i) * 2], wn1 = Wih[(64 + i) * 2 + 1];
    const float br  = bih[i] + bhh[i];
    const float bz  = bih[32 + i] + bhh[32 + i];
    const float bni = bih[64 + i];
    const float bnh = bhh[64 + i];

    // LDS: staged inputs + transposed h history (row stride 225 -> conflict-free)
    __shared__ float2 sx[LMAX + WARMUP + 4];
    __shared__ float  hh[32 * (LMAX + 1)];     // hh[i*225 + step]
    for (int j = lane; j < cnt + 1; j += 64) {
        int idx = s0 - 1 + j;
        idx = idx < 0 ? 0 : idx;
        int t = spk[idx];
        sx[j] = make_float2((float)t, x[t]);
    }
    __syncthreads();

    float hs[32];
    #pragma unroll
    for (int k = 0; k < 32; k++) hs[k] = 0.f;
    float hold = 0.f;

    float2 p0 = sx[0], p1 = sx[1];
    const int hbase = i * (LMAX + 1);
    for (int j = 0; j < cnt; ++j) {
        float2 p2 = sx[j + 2 < cnt ? j + 2 : cnt];
        float d  = (p1.x - p0.x) * 0.0078125f;
        float xt = p1.y;

        float ar0 = fmaf(wr1, d, fmaf(wr0, xt, br)), ar1 = 0.f, ar2 = 0.f, ar3 = 0.f;
        float az0 = fmaf(wz1, d, fmaf(wz0, xt, bz)), az1 = 0.f, az2 = 0.f, az3 = 0.f;
        float an0 = bnh, an1 = 0.f, an2 = 0.f, an3 = 0.f;
        float gin = fmaf(wn1, d, fmaf(wn0, xt, bni));
        #pragma unroll
        for (int k = 0; k < 8; k++) {      // 12 chains of depth 8, 96 FMAs
            ar0 = fmaf(Wr[k],      hs[k],      ar0);
            ar1 = fmaf(Wr[k +  8], hs[k +  8], ar1);
            ar2 = fmaf(Wr[k + 16], hs[k + 16], ar2);
            ar3 = fmaf(Wr[k + 24], hs[k + 24], ar3);
            az0 = fmaf(Wz[k],      hs[k],      az0);
            az1 = fmaf(Wz[k +  8], hs[k +  8], az1);
            az2 = fmaf(Wz[k + 16], hs[k + 16], az2);
            az3 = fmaf(Wz[k + 24], hs[k + 24], az3);
            an0 = fmaf(Wn[k],      hs[k],      an0);
            an1 = fmaf(Wn[k +  8], hs[k +  8], an1);
            an2 = fmaf(Wn[k + 16], hs[k + 16], an2);
            an3 = fmaf(Wn[k + 24], hs[k + 24], an3);
        }
        float ar = (ar0 + ar1) + (ar2 + ar3);
        float az = (az0 + az1) + (az2 + az3);
        float an = (an0 + an1) + (an2 + an3);

        float r = __builtin_amdgcn_rcpf(1.f + __builtin_amdgcn_exp2f(-1.44269504089f * ar));
        float z = __builtin_amdgcn_rcpf(1.f + __builtin_amdgcn_exp2f(-1.44269504089f * az));
        float npre = fmaf(r, an, gin);
        float en = __builtin_amdgcn_exp2f(2.88539008178f * npre);
        float n = fmaf(-2.f, __builtin_amdgcn_rcpf(1.f + en), 1.f);
        float hnew = fmaf(z, hold - n, n);
        hold = hnew;
        if (j >= jw && lane < 32)
            hh[hbase + (j - jw)] = hnew;             // LDS only, no global store
        int hb = __float_as_int(hnew);
        #pragma unroll
        for (int k = 0; k < 32; k++)
            hs[k] = __int_as_float(__builtin_amdgcn_readlane(hb, k));
        p0 = p1; p1 = p2;
    }
    __syncthreads();

    // epilogue: A/B dot products from LDS h history (reads conflict-free:
    // for fixed k, bank = (k + idx) % 32, idx = lane-varying)
    const float bvv = *bv, bss = *bs;
    for (int s = start + lane; s < end; s += 64) {
        int idx = s - start;
        float a = bvv, b = bss;
        #pragma unroll
        for (int k = 0; k < 32; k++) {
            float hv = hh[k * (LMAX + 1) + idx];
            a = fmaf(hv, Wv[k], a);
            b = fmaf(hv, Wsc[k], b);
        }
        A[s] = a; B[s] = b;
    }
}

// ---- K5: expand outputs over all t ----
__global__ __launch_bounds__(256) void k_out(const int* __restrict__ seg,
                                             const int* __restrict__ spk,
                                             const float* __restrict__ A,
                                             const float* __restrict__ B,
                                             float* __restrict__ out)
{
    int t = blockIdx.x * 256 + threadIdx.x;
    int p = seg[t];
    int tp = spk[p];
    out[t] = fmaf(B[p], (float)(t - tp) * 0.0078125f, A[p]);
}

extern "C" void kernel_launch(void* const* d_in, const int* in_sizes, int n_in,
                              void* d_out, int out_size, void* d_ws, size_t ws_size,
                              hipStream_t stream)
{
    const float* x   = (const float*)d_in[0];
    const float* Wih = (const float*)d_in[1];
    const float* Whh = (const float*)d_in[2];
    const float* bih = (const float*)d_in[3];
    const float* bhh = (const float*)d_in[4];
    const float* Wv  = (const float*)d_in[5];
    const float* bv  = (const float*)d_in[6];
    const float* Wsc = (const float*)d_in[7];
    const float* bs  = (const float*)d_in[8];
    float* out = (float*)d_out;

    char* ws = (char*)d_ws;
    uint8_t* mask = (uint8_t*)(ws + OFF_MASK);
    int*    seg   = (int*)(ws + OFF_SEG);
    int*    spk   = (int*)(ws + OFF_SPK);
    float*  A     = (float*)(ws + OFF_A);
    float*  B     = (float*)(ws + OFF_B);
    int*    cnt   = (int*)(ws + OFF_CNT);
    int*    boff  = (int*)(ws + OFF_BOFF);
    int*    nspk  = (int*)(ws + OFF_N);

    k_mask<<<512, 256, 0, stream>>>(x, mask, out, out_size, cnt);
    k_scan<<<1, 512, 0, stream>>>(cnt, boff, nspk, out, out_size);
    k_scatter<<<512, 256, 0, stream>>>(mask, boff, seg, spk);
    k_chain<<<NCHUNK, 64, 0, stream>>>(Whh, Wih, bih, bhh, spk, x, nspk,
                                       Wv, Wsc, bv, bs, A, B);
    k_out<<<2048, 256, 0, stream>>>(seg, spk, A, B, out);
}

// Round 4
// 157.519 us; speedup vs baseline: 1.9807x; 1.1716x over previous
//
#include <hip/hip_runtime.h>
#include <stdint.h>

#define T_LEN 524288
#define NBLK 2048
#define SEGL 80           // spikes per chunk (N=161792 -> 2023 chunks)
#define WARMUP 48
#define HROW (SEGL + 1)   // 81 words, odd stride -> conflict-free

// ---- workspace layout (bytes) ----
static const size_t OFF_MASK = 0;                       // T uint8
static const size_t OFF_SEG  = 524288;                  // T int
static const size_t OFF_SPK  = OFF_SEG + 4ull*T_LEN;    // T int
static const size_t OFF_A    = OFF_SPK + 4ull*T_LEN;    // T float
static const size_t OFF_B    = OFF_A + 4ull*T_LEN;      // T float
static const size_t OFF_CNT  = OFF_B + 4ull*T_LEN;      // 512 int
static const size_t OFF_BOFF = OFF_CNT + 4ull*512;      // 512 int
static const size_t OFF_N    = OFF_BOFF + 4ull*512;     // 1 int

// ---- K1: spike mask (fp32 rolling window RMS) + per-1024-block spike count ----
__global__ __launch_bounds__(256) void k_mask(const float* __restrict__ x,
                                              uint8_t* __restrict__ mask,
                                              float* __restrict__ out, int out_size,
                                              int* __restrict__ cnt)
{
    __shared__ float tile[1154];          // x[bs-130 .. bs+1024)
    __shared__ int tot;
    const int bs = blockIdx.x * 1024;
    const int tid = threadIdx.x;
    if (tid == 0) tot = 0;
    for (int j = tid; j < 1154; j += 256) {
        int g = bs - 130 + j;
        tile[j] = (g >= 0) ? x[g] : 0.f;
    }
    __syncthreads();

    const int loc = tid * 4;
    float s = 0.f;
    #pragma unroll 16
    for (int m = 0; m < 128; ++m) {
        float v = tile[loc + 2 + m];
        s = fmaf(v, v, s);
    }
    uchar4 mv;
    float4 mf;
    int msum = 0;
    uint8_t* mp = &mv.x;
    float*   fp = &mf.x;
    #pragma unroll
    for (int it = 0; it < 4; ++it) {
        int t = bs + loc + it;
        int c = t < 128 ? (t < 1 ? 1 : t) : 128;
        float rms = sqrtf(fmaxf(s, 0.f) / (float)c) + 1e-8f;
        float xt = tile[loc + 130 + it];
        float pr = 2.f * tile[loc + 129 + it] - tile[loc + 128 + it];
        float err = fabsf(xt - pr);
        bool m = (t < 2) || (err > 2.5f * rms);
        mp[it] = m ? 1 : 0;
        fp[it] = m ? 1.f : 0.f;
        msum += m ? 1 : 0;
        float a = tile[loc + 130 + it], d = tile[loc + 2 + it];
        s = fmaf(a, a, s) - d * d;
    }
    *(uchar4*)(mask + bs + loc) = mv;
    int oi = T_LEN + 1 + bs + loc;
    if (oi + 3 < out_size) *(float4*)(out + oi) = mf;

    for (int d = 32; d; d >>= 1) msum += __shfl_down(msum, d, 64);
    if ((tid & 63) == 0) atomicAdd(&tot, msum);
    __syncthreads();
    if (tid == 0) cnt[blockIdx.x] = tot;
}

// ---- K2: scan of 512 block counts ----
__global__ __launch_bounds__(512) void k_scan(const int* __restrict__ cnt,
                                              int* __restrict__ boff,
                                              int* __restrict__ nspk,
                                              float* __restrict__ out, int out_size)
{
    __shared__ int buf[2][512];
    int t = threadIdx.x;
    int v = cnt[t];
    buf[0][t] = v;
    __syncthreads();
    int src = 0;
    for (int d = 1; d < 512; d <<= 1) {
        int nv = buf[src][t] + (t >= d ? buf[src][t - d] : 0);
        buf[src ^ 1][t] = nv;
        __syncthreads();
        src ^= 1;
    }
    boff[t] = buf[src][t] - v;
    if (t == 511) {
        int tot = buf[src][511];
        *nspk = tot;
        if (T_LEN < out_size) out[T_LEN] = (float)tot;
    }
}

// ---- K3: scatter spike times + per-t segment index ----
__global__ __launch_bounds__(256) void k_scatter(const uint8_t* __restrict__ mask,
                                                 const int* __restrict__ boff,
                                                 int* __restrict__ seg,
                                                 int* __restrict__ spk)
{
    __shared__ int wtot[4];
    const int tid = threadIdx.x, b = blockIdx.x;
    const int base = b * 1024 + tid * 4;
    uchar4 mv = *(const uchar4*)(mask + base);
    int m0 = mv.x, m1 = mv.y, m2 = mv.z, m3 = mv.w;
    int e1 = m0, e2 = m0 + m1, e3 = m0 + m1 + m2, tsum = e3 + m3;
    int lane = tid & 63, w = tid >> 6;
    int incl = tsum;
    for (int d = 1; d < 64; d <<= 1) {
        int u = __shfl_up(incl, d, 64);
        if (lane >= d) incl += u;
    }
    if (lane == 63) wtot[w] = incl;
    __syncthreads();
    int woff = 0;
    for (int i = 0; i < w; i++) woff += wtot[i];
    int texcl = woff + incl - tsum;
    int g0 = boff[b] + texcl;
    int e[4] = {0, e1, e2, e3};
    int m[4] = {m0, m1, m2, m3};
    #pragma unroll
    for (int k = 0; k < 4; k++) {
        int excl = g0 + e[k];
        seg[base + k] = excl + m[k] - 1;
        if (m[k]) spk[excl] = base + k;
    }
}

// ---- K4: sequential GRU chain, k-split across wave halves ----
// lane = i + 32*p: partial dot over k in [16p,16p+16) for gates r_i,z_i,n_i.
// Combine halves via ds_bpermute(xor 32); h broadcast via 16 ds_bpermute into
// per-lane VGPRs. h history -> LDS (odd stride), A/B in epilogue.
__global__ __attribute__((amdgpu_waves_per_eu(2, 2)))
__launch_bounds__(64) void k_chain(const float* __restrict__ Whh,
                                   const float* __restrict__ Wih,
                                   const float* __restrict__ bih,
                                   const float* __restrict__ bhh,
                                   const int* __restrict__ spk,
                                   const float* __restrict__ x,
                                   const int* __restrict__ nspk,
                                   const float* __restrict__ Wv,
                                   const float* __restrict__ Wsc,
                                   const float* __restrict__ bv,
                                   const float* __restrict__ bs,
                                   float* __restrict__ A,
                                   float* __restrict__ B)
{
    const int lane = threadIdx.x;
    const int N = *nspk;
    const int i = lane & 31;
    const int p = lane >> 5;

    // per-lane half-row weights (VGPRs)
    float Wr[16], Wz[16], Wn[16];
    #pragma unroll
    for (int k = 0; k < 16; k++) {
        Wr[k] = Whh[i * 32        + 16 * p + k];
        Wz[k] = Whh[(32 + i) * 32 + 16 * p + k];
        Wn[k] = Whh[(64 + i) * 32 + 16 * p + k];
    }
    // input weights / biases: r,z,bnh only on half 0 (avoid double-count);
    // gin (input part of n) full on both halves.
    const float z0 = p ? 0.f : 1.f;
    const float wr0 = z0 * Wih[i * 2],        wr1 = z0 * Wih[i * 2 + 1];
    const float wz0 = z0 * Wih[(32 + i) * 2], wz1 = z0 * Wih[(32 + i) * 2 + 1];
    const float br  = z0 * (bih[i] + bhh[i]);
    const float bz  = z0 * (bih[32 + i] + bhh[32 + i]);
    const float bnh = z0 * bhh[64 + i];
    const float wn0 = Wih[(64 + i) * 2], wn1 = Wih[(64 + i) * 2 + 1];
    const float bni = bih[64 + i];

    __shared__ float  hh[33 * HROW + 32];     // 32 rows + dummy sink row
    __shared__ float2 sx[SEGL + WARMUP + 4];

    const int bidx = 64 * p;                  // bpermute byte base: lane 16p
    const int xidx = (lane ^ 32) * 4;         // xor-32 combine index

    for (int c = blockIdx.x; c * SEGL < N; c += NBLK) {
        const int start = c * SEGL;
        const int end = min(start + SEGL, N);
        const int s0 = max(start - WARMUP, 0);
        const int cnt = end - s0;
        const int jw = start - s0;

        for (int j = lane; j < cnt + 3; j += 64) {
            int idx = min(max(s0 - 1 + j, 0), N - 1);
            int t = spk[idx];
            sx[j] = make_float2((float)t, x[t]);
        }
        __syncthreads();

        float hs[16];
        #pragma unroll
        for (int k = 0; k < 16; k++) hs[k] = 0.f;
        float hold = 0.f;

        float2 p0 = sx[0], p1 = sx[1];
        for (int j = 0; j < cnt; ++j) {
            float2 p2 = sx[j + 2];
            float d  = (p1.x - p0.x) * 0.0078125f;
            float xt = p1.y;

            float ar0 = fmaf(wr1, d, fmaf(wr0, xt, br)), ar1 = 0.f;
            float az0 = fmaf(wz1, d, fmaf(wz0, xt, bz)), az1 = 0.f;
            float an0 = bnh, an1 = 0.f;
            float gin = fmaf(wn1, d, fmaf(wn0, xt, bni));
            #pragma unroll
            for (int k = 0; k < 8; k++) {     // 48 FMAs, 6 chains of depth 8
                ar0 = fmaf(Wr[k],     hs[k],     ar0);
                ar1 = fmaf(Wr[k + 8], hs[k + 8], ar1);
                az0 = fmaf(Wz[k],     hs[k],     az0);
                az1 = fmaf(Wz[k + 8], hs[k + 8], az1);
                an0 = fmaf(Wn[k],     hs[k],     an0);
                an1 = fmaf(Wn[k + 8], hs[k + 8], an1);
            }
            float ar = ar0 + ar1, az = az0 + az1, an = an0 + an1;
            // combine the two k-halves (xor-32 bpermute)
            ar += __int_as_float(__builtin_amdgcn_ds_bpermute(xidx, __float_as_int(ar)));
            az += __int_as_float(__builtin_amdgcn_ds_bpermute(xidx, __float_as_int(az)));
            an += __int_as_float(__builtin_amdgcn_ds_bpermute(xidx, __float_as_int(an)));

            float r = __builtin_amdgcn_rcpf(1.f + __builtin_amdgcn_exp2f(-1.44269504089f * ar));
            float z = __builtin_amdgcn_rcpf(1.f + __builtin_amdgcn_exp2f(-1.44269504089f * az));
            float npre = fmaf(r, an, gin);
            float en = __builtin_amdgcn_exp2f(2.88539008178f * npre);
            float n = fmaf(-2.f, __builtin_amdgcn_rcpf(1.f + en), 1.f);
            float hnew = fmaf(z, hold - n, n);
            hold = hnew;

            // branch-free h store: lower half & j>=jw -> real slot, else dummy row
            bool okst = (p == 0) & (j >= jw);
            int addr = okst ? (i * HROW + (j - jw)) : (33 * HROW + i);
            hh[addr] = hnew;

            // broadcast: hs[k] = h[16p+k] via bpermute
            int hb = __float_as_int(hnew);
            #pragma unroll
            for (int k = 0; k < 16; k++)
                hs[k] = __int_as_float(__builtin_amdgcn_ds_bpermute(bidx + 4 * k, hb));
            p0 = p1; p1 = p2;
        }
        __syncthreads();

        // epilogue: A/B dot products from LDS h history
        const float bvv = *bv, bss = *bs;
        for (int s = start + lane; s < end; s += 64) {
            int idx = s - start;
            float a = bvv, b = bss;
            #pragma unroll
            for (int k = 0; k < 32; k++) {
                float hv = hh[k * HROW + idx];
                a = fmaf(hv, Wv[k], a);
                b = fmaf(hv, Wsc[k], b);
            }
            A[s] = a; B[s] = b;
        }
        __syncthreads();
    }
}

// ---- K5: expand outputs over all t ----
__global__ __launch_bounds__(256) void k_out(const int* __restrict__ seg,
                                             const int* __restrict__ spk,
                                             const float* __restrict__ A,
                                             const float* __restrict__ B,
                                             float* __restrict__ out)
{
    int t = blockIdx.x * 256 + threadIdx.x;
    int p = seg[t];
    int tp = spk[p];
    out[t] = fmaf(B[p], (float)(t - tp) * 0.0078125f, A[p]);
}

extern "C" void kernel_launch(void* const* d_in, const int* in_sizes, int n_in,
                              void* d_out, int out_size, void* d_ws, size_t ws_size,
                              hipStream_t stream)
{
    const float* x   = (const float*)d_in[0];
    const float* Wih = (const float*)d_in[1];
    const float* Whh = (const float*)d_in[2];
    const float* bih = (const float*)d_in[3];
    const float* bhh = (const float*)d_in[4];
    const float* Wv  = (const float*)d_in[5];
    const float* bv  = (const float*)d_in[6];
    const float* Wsc = (const float*)d_in[7];
    const float* bs  = (const float*)d_in[8];
    float* out = (float*)d_out;

    char* ws = (char*)d_ws;
    uint8_t* mask = (uint8_t*)(ws + OFF_MASK);
    int*    seg   = (int*)(ws + OFF_SEG);
    int*    spk   = (int*)(ws + OFF_SPK);
    float*  A     = (float*)(ws + OFF_A);
    float*  B     = (float*)(ws + OFF_B);
    int*    cnt   = (int*)(ws + OFF_CNT);
    int*    boff  = (int*)(ws + OFF_BOFF);
    int*    nspk  = (int*)(ws + OFF_N);

    k_mask<<<512, 256, 0, stream>>>(x, mask, out, out_size, cnt);
    k_scan<<<1, 512, 0, stream>>>(cnt, boff, nspk, out, out_size);
    k_scatter<<<512, 256, 0, stream>>>(mask, boff, seg, spk);
    k_chain<<<NBLK, 64, 0, stream>>>(Whh, Wih, bih, bhh, spk, x, nspk,
                                     Wv, Wsc, bv, bs, A, B);
    k_out<<<2048, 256, 0, stream>>>(seg, spk, A, B, out);
}

// Round 5
// 144.677 us; speedup vs baseline: 2.1565x; 1.0888x over previous
//
#include <hip/hip_runtime.h>
#include <stdint.h>

#define T_LEN 524288
#define NBLK 2048         // blocks of 128 (2 waves) -> 4096 wave slots
#define SEGL 40           // spikes per chunk (N=161792 -> 4045 chunks)
#define WARMUP 32
#define HROW (SEGL + 1)   // 41, odd stride -> conflict-free

// ---- workspace layout (bytes) ----
static const size_t OFF_MASK = 0;                       // T uint8
static const size_t OFF_SPK  = 524288;                  // T int
static const size_t OFF_CNT  = OFF_SPK + 4ull*T_LEN;    // 512 int
static const size_t OFF_BOFF = OFF_CNT + 4ull*512;      // 512 int
static const size_t OFF_N    = OFF_BOFF + 4ull*512;     // 1 int

// fast tanh: Eigen-style rational approx, |err| ~ few ulp on [-7.9, 7.9]
__device__ __forceinline__ float tanh_fast(float x) {
    const float mx = 7.90531110763549805f;
    float y = fminf(fmaxf(x, -mx), mx);
    float t = y * y;
    float p = fmaf(t, -2.76076847742355e-16f, 2.00018790482477e-13f);
    p = fmaf(t, p, -8.60467152213735e-11f);
    p = fmaf(t, p, 5.12229709037114e-08f);
    p = fmaf(t, p, 1.48572235717979e-05f);
    p = fmaf(t, p, 6.37261928875436e-04f);
    p = fmaf(t, p, 4.89352455891786e-03f);
    p = p * y;
    float q = fmaf(t, 1.19825839466702e-06f, 1.18534705686654e-04f);
    q = fmaf(t, q, 2.26843463243900e-03f);
    q = fmaf(t, q, 4.89352518554385e-03f);
    return p * __builtin_amdgcn_rcpf(q);
}
__device__ __forceinline__ float sigmoid_fast(float x) {
    return fmaf(0.5f, tanh_fast(0.5f * x), 0.5f);
}

// ---- K1: spike mask (fp32 rolling window RMS) + per-1024-block spike count ----
__global__ __launch_bounds__(256) void k_mask(const float* __restrict__ x,
                                              uint8_t* __restrict__ mask,
                                              float* __restrict__ out, int out_size,
                                              int* __restrict__ cnt)
{
    __shared__ float tile[1154];          // x[bs-130 .. bs+1024)
    __shared__ int tot;
    const int bs = blockIdx.x * 1024;
    const int tid = threadIdx.x;
    if (tid == 0) tot = 0;
    for (int j = tid; j < 1154; j += 256) {
        int g = bs - 130 + j;
        tile[j] = (g >= 0) ? x[g] : 0.f;
    }
    __syncthreads();

    const int loc = tid * 4;
    float s = 0.f;
    #pragma unroll 16
    for (int m = 0; m < 128; ++m) {
        float v = tile[loc + 2 + m];
        s = fmaf(v, v, s);
    }
    uchar4 mv;
    float4 mf;
    int msum = 0;
    uint8_t* mp = &mv.x;
    float*   fp = &mf.x;
    #pragma unroll
    for (int it = 0; it < 4; ++it) {
        int t = bs + loc + it;
        int c = t < 128 ? (t < 1 ? 1 : t) : 128;
        float rms = sqrtf(fmaxf(s, 0.f) / (float)c) + 1e-8f;
        float xt = tile[loc + 130 + it];
        float pr = 2.f * tile[loc + 129 + it] - tile[loc + 128 + it];
        float err = fabsf(xt - pr);
        bool m = (t < 2) || (err > 2.5f * rms);
        mp[it] = m ? 1 : 0;
        fp[it] = m ? 1.f : 0.f;
        msum += m ? 1 : 0;
        float a = tile[loc + 130 + it], d = tile[loc + 2 + it];
        s = fmaf(a, a, s) - d * d;
    }
    *(uchar4*)(mask + bs + loc) = mv;
    int oi = T_LEN + 1 + bs + loc;
    if (oi + 3 < out_size) *(float4*)(out + oi) = mf;

    for (int d = 32; d; d >>= 1) msum += __shfl_down(msum, d, 64);
    if ((tid & 63) == 0) atomicAdd(&tot, msum);
    __syncthreads();
    if (tid == 0) cnt[blockIdx.x] = tot;
}

// ---- K2: scan of 512 block counts ----
__global__ __launch_bounds__(512) void k_scan(const int* __restrict__ cnt,
                                              int* __restrict__ boff,
                                              int* __restrict__ nspk,
                                              float* __restrict__ out, int out_size)
{
    __shared__ int buf[2][512];
    int t = threadIdx.x;
    int v = cnt[t];
    buf[0][t] = v;
    __syncthreads();
    int src = 0;
    for (int d = 1; d < 512; d <<= 1) {
        int nv = buf[src][t] + (t >= d ? buf[src][t - d] : 0);
        buf[src ^ 1][t] = nv;
        __syncthreads();
        src ^= 1;
    }
    boff[t] = buf[src][t] - v;
    if (t == 511) {
        int tot = buf[src][511];
        *nspk = tot;
        if (T_LEN < out_size) out[T_LEN] = (float)tot;
    }
}

// ---- K3: scatter spike times ----
__global__ __launch_bounds__(256) void k_scatter(const uint8_t* __restrict__ mask,
                                                 const int* __restrict__ boff,
                                                 int* __restrict__ spk)
{
    __shared__ int wtot[4];
    const int tid = threadIdx.x, b = blockIdx.x;
    const int base = b * 1024 + tid * 4;
    uchar4 mv = *(const uchar4*)(mask + base);
    int m0 = mv.x, m1 = mv.y, m2 = mv.z, m3 = mv.w;
    int e1 = m0, e2 = m0 + m1, e3 = m0 + m1 + m2, tsum = e3 + m3;
    int lane = tid & 63, w = tid >> 6;
    int incl = tsum;
    for (int d = 1; d < 64; d <<= 1) {
        int u = __shfl_up(incl, d, 64);
        if (lane >= d) incl += u;
    }
    if (lane == 63) wtot[w] = incl;
    __syncthreads();
    int woff = 0;
    for (int i = 0; i < w; i++) woff += wtot[i];
    int texcl = woff + incl - tsum;
    int g0 = boff[b] + texcl;
    int e[4] = {0, e1, e2, e3};
    int m[4] = {m0, m1, m2, m3};
    #pragma unroll
    for (int k = 0; k < 4; k++) {
        int excl = g0 + e[k];
        if (m[k]) spk[excl] = base + k;
    }
}

// per-wave LDS region
struct __align__(16) WaveLds {
    float  hh[32 * HROW + 32];     // h history (+ sink row)
    float2 sx[SEGL + WARMUP + 8];  // staged (t, x_t)
    float  hbc[64];                // h broadcast / later a,b scalars
};

// ---- K4: sequential GRU chain (k-split) + fused output expansion ----
// wave = one chunk. lane = i + 32*p: partial dots over k in [16p,16p+16).
// Combine halves via 3 x ds_bpermute(xor 32). Broadcast h via 1 ds_write +
// 4 ds_read_b128 (uniform per half). No barriers: waves fully independent.
__global__ __attribute__((amdgpu_waves_per_eu(4, 8)))
__launch_bounds__(128) void k_chain(const float* __restrict__ Whh,
                                    const float* __restrict__ Wih,
                                    const float* __restrict__ bih,
                                    const float* __restrict__ bhh,
                                    const int* __restrict__ spk,
                                    const float* __restrict__ x,
                                    const int* __restrict__ nspk,
                                    const float* __restrict__ Wv,
                                    const float* __restrict__ Wsc,
                                    const float* __restrict__ bv,
                                    const float* __restrict__ bs,
                                    float* __restrict__ out)
{
    __shared__ WaveLds lds[2];
    const int w = threadIdx.x >> 6;
    const int lane = threadIdx.x & 63;
    const int N = *nspk;
    const int i = lane & 31;
    const int p = lane >> 5;
    WaveLds& L = lds[w];

    // per-lane half-row weights (VGPRs)
    float Wr[16], Wz[16], Wn[16];
    #pragma unroll
    for (int k = 0; k < 16; k++) {
        Wr[k] = Whh[i * 32        + 16 * p + k];
        Wz[k] = Whh[(32 + i) * 32 + 16 * p + k];
        Wn[k] = Whh[(64 + i) * 32 + 16 * p + k];
    }
    const float z0 = p ? 0.f : 1.f;       // input terms only on half 0
    const float wr0 = z0 * Wih[i * 2],        wr1 = z0 * Wih[i * 2 + 1];
    const float wz0 = z0 * Wih[(32 + i) * 2], wz1 = z0 * Wih[(32 + i) * 2 + 1];
    const float br  = z0 * (bih[i] + bhh[i]);
    const float bz  = z0 * (bih[32 + i] + bhh[32 + i]);
    const float bnh = z0 * bhh[64 + i];
    const float wn0 = z0 * Wih[(64 + i) * 2], wn1 = z0 * Wih[(64 + i) * 2 + 1];
    const float bni = z0 * bih[64 + i];

    const int xidx = (lane ^ 32) * 4;     // xor-32 combine index
    const int wid0 = blockIdx.x * 2 + w;
    const int wstride = NBLK * 2;

    for (int c = wid0; c * SEGL < N; c += wstride) {
        const int start = c * SEGL;
        const int end = min(start + SEGL, N);
        const int s0 = max(start - WARMUP, 0);
        const int cnt = end - s0;
        const int jw = start - s0;

        for (int j = lane; j < cnt + 3; j += 64) {
            int idx = min(max(s0 - 1 + j, 0), N - 1);
            int t = spk[idx];
            L.sx[j] = make_float2((float)t, x[t]);
        }
        __builtin_amdgcn_wave_barrier();

        float hs[16];
        #pragma unroll
        for (int k = 0; k < 16; k++) hs[k] = 0.f;
        float hold = 0.f;

        float2 p0 = L.sx[0], p1 = L.sx[1];
        for (int j = 0; j < cnt; ++j) {
            float2 p2 = L.sx[j + 2];
            float d  = (p1.x - p0.x) * 0.0078125f;
            float xt = p1.y;

            float ar0 = fmaf(wr1, d, fmaf(wr0, xt, br)), ar1 = 0.f;
            float az0 = fmaf(wz1, d, fmaf(wz0, xt, bz)), az1 = 0.f;
            float an0 = bnh, an1 = 0.f;
            float gin = fmaf(wn1, d, fmaf(wn0, xt, bni));
            #pragma unroll
            for (int k = 0; k < 8; k++) {     // 48 FMAs, 6 chains of depth 8
                ar0 = fmaf(Wr[k],     hs[k],     ar0);
                ar1 = fmaf(Wr[k + 8], hs[k + 8], ar1);
                az0 = fmaf(Wz[k],     hs[k],     az0);
                az1 = fmaf(Wz[k + 8], hs[k + 8], az1);
                an0 = fmaf(Wn[k],     hs[k],     an0);
                an1 = fmaf(Wn[k + 8], hs[k + 8], an1);
            }
            float ar = ar0 + ar1, az = az0 + az1, an = an0 + an1;
            float gn = gin;
            ar += __int_as_float(__builtin_amdgcn_ds_bpermute(xidx, __float_as_int(ar)));
            az += __int_as_float(__builtin_amdgcn_ds_bpermute(xidx, __float_as_int(az)));
            float anx = an + __int_as_float(__builtin_amdgcn_ds_bpermute(xidx, __float_as_int(an)));
            float gnx = gn + __int_as_float(__builtin_amdgcn_ds_bpermute(xidx, __float_as_int(gn)));

            float r = sigmoid_fast(ar);
            float z = sigmoid_fast(az);
            float n = tanh_fast(fmaf(r, anx, gnx));
            float hnew = fmaf(z, hold - n, n);
            hold = hnew;

            // h history (both halves write identical value; warmup -> sink row)
            int addr = (j >= jw) ? (i * HROW + (j - jw)) : (32 * HROW + i);
            L.hh[addr] = hnew;

            // broadcast: write h_i, read own 16-half as 4 x float4 (uniform/half)
            L.hbc[i] = hnew;
            float4* hb4 = (float4*)&L.hbc[16 * p];
            float4 h0 = hb4[0], h1 = hb4[1], h2 = hb4[2], h3 = hb4[3];
            hs[0]=h0.x; hs[1]=h0.y; hs[2]=h0.z; hs[3]=h0.w;
            hs[4]=h1.x; hs[5]=h1.y; hs[6]=h1.z; hs[7]=h1.w;
            hs[8]=h2.x; hs[9]=h2.y; hs[10]=h2.z; hs[11]=h2.w;
            hs[12]=h3.x; hs[13]=h3.y; hs[14]=h3.z; hs[15]=h3.w;
            p0 = p1; p1 = p2;
        }
        __builtin_amdgcn_wave_barrier();

        // epilogue 1: a,b per spike (lanes 0..31) -> reuse hbc
        const float bvv = *bv, bss = *bs;
        if (lane < 32) {
            int s = start + lane;
            float a = bvv, b = bss;
            #pragma unroll
            for (int k = 0; k < 32; k++) {
                float hv = L.hh[k * HROW + lane];
                a = fmaf(hv, Wv[k], a);
                b = fmaf(hv, Wsc[k], b);
            }
            L.hbc[lane] = a;
            L.hbc[32 + lane] = b;
        }
        __builtin_amdgcn_wave_barrier();

        // epilogue 2: expand out[t] for t in [spk[start], t_hi)
        const int tlo = (int)L.sx[jw + 1].x;
        const int thi = (end == N) ? T_LEN : (int)L.sx[cnt + 1].x;
        for (int t = tlo + lane; t < thi; t += 64) {
            float tf = (float)t;
            int lo = jw + 1, hi = cnt;        // sx idx range of spikes [start,end)
            #pragma unroll
            for (int itb = 0; itb < 6; ++itb) {
                int mid = (lo + hi + 1) >> 1;
                bool le = L.sx[mid].x <= tf;
                lo = le ? mid : lo;
                hi = le ? hi : mid - 1;
            }
            int sp = lo - (jw + 1);           // spike index - start
            float a = L.hbc[sp], b = L.hbc[32 + sp];
            float tp = L.sx[lo].x;
            out[t] = fmaf(b, (tf - tp) * 0.0078125f, a);
        }
        __builtin_amdgcn_wave_barrier();
    }
}

extern "C" void kernel_launch(void* const* d_in, const int* in_sizes, int n_in,
                              void* d_out, int out_size, void* d_ws, size_t ws_size,
                              hipStream_t stream)
{
    const float* x   = (const float*)d_in[0];
    const float* Wih = (const float*)d_in[1];
    const float* Whh = (const float*)d_in[2];
    const float* bih = (const float*)d_in[3];
    const float* bhh = (const float*)d_in[4];
    const float* Wv  = (const float*)d_in[5];
    const float* bv  = (const float*)d_in[6];
    const float* Wsc = (const float*)d_in[7];
    const float* bs  = (const float*)d_in[8];
    float* out = (float*)d_out;

    char* ws = (char*)d_ws;
    uint8_t* mask = (uint8_t*)(ws + OFF_MASK);
    int*    spk   = (int*)(ws + OFF_SPK);
    int*    cnt   = (int*)(ws + OFF_CNT);
    int*    boff  = (int*)(ws + OFF_BOFF);
    int*    nspk  = (int*)(ws + OFF_N);

    k_mask<<<512, 256, 0, stream>>>(x, mask, out, out_size, cnt);
    k_scan<<<1, 512, 0, stream>>>(cnt, boff, nspk, out, out_size);
    k_scatter<<<512, 256, 0, stream>>>(mask, boff, spk);
    k_chain<<<NBLK, 128, 0, stream>>>(Whh, Wih, bih, bhh, spk, x, nspk,
                                      Wv, Wsc, bv, bs, out);
}